// Round 18
// baseline (77.032 us; speedup 1.0000x reference)
//
#include <hip/hip_runtime.h>

#define B_TOT 2048
#define NHEAD 3

typedef __attribute__((ext_vector_type(8))) short short8v;
typedef __attribute__((ext_vector_type(4))) float f32x4;
typedef __attribute__((ext_vector_type(2))) __fp16 f16x2;

#define LOG2E 1.4426950408889634f

static __device__ __forceinline__ unsigned short f2bf(float x) {
    unsigned u = __builtin_bit_cast(unsigned, x);
    u += 0x7FFFu + ((u >> 16) & 1u);
    return (unsigned short)(u >> 16);
}
static __device__ __forceinline__ float bf2f(unsigned short s) {
    unsigned u = ((unsigned)s) << 16;
    return __builtin_bit_cast(float, u);
}
static __device__ __forceinline__ float exp2_fast(float x) {
    float r; asm("v_exp_f32 %0, %1" : "=v"(r) : "v"(x)); return r;
}

// ---------------------------------------------------------------------------
// Bias MLP precompute, 4-way j-split (passed r17). Layout (verified r7-r17):
//   bias2[((h*16 + mt*4 + nt) * 64 + lane) * 4 + r], pre-scaled by log2e.
// ---------------------------------------------------------------------------
__global__ __launch_bounds__(256) void bias_kernel(const float* __restrict__ w1,
                                                   const float* __restrict__ b1,
                                                   const float* __restrict__ w2,
                                                   const float* __restrict__ b2,
                                                   float* __restrict__ bias2) {
    int gtid = blockIdx.x * 256 + threadIdx.x;   // 0..49151
    int t = gtid >> 2, sub = gtid & 3;           // t: output index 0..12287
    int h = t >> 12;
    int lane = (t >> 6) & 63;
    int pair = t & 63;
    int g = lane >> 4, c = lane & 15;
    int mt = pair >> 4, nt = (pair >> 2) & 3, r = pair & 3;
    int n = 16 * mt + 4 * g + r;
    int m = 16 * nt + c;

    float d0 = (float)((n >> 3) - (m >> 3));
    float d1 = (float)((n & 7) - (m & 7));
    float r0 = (d0 > 0.f ? 1.f : (d0 < 0.f ? -1.f : 0.f)) * log1pf(fabsf(d0));
    float r1 = (d1 > 0.f ? 1.f : (d1 < 0.f ? -1.f : 0.f)) * log1pf(fabsf(d1));
    float a = 0.f;
    for (int i = 0; i < 64; i++) {
        int j = 4 * i + sub;
        float hd = fmaf(r0, w1[j], fmaf(r1, w1[256 + j], b1[j]));
        hd = fmaxf(hd, 0.f);
        a = fmaf(hd, w2[j * 3 + h], a);
    }
    a += __shfl_xor(a, 1, 64);
    a += __shfl_xor(a, 2, 64);
    if (sub == 0)
        bias2[((h * 16 + mt * 4 + nt) * 64 + lane) * 4 + r] = (a + b2[h]) * LOG2E;
}

// ---------------------------------------------------------------------------
// Main kernel: TWO (b,h) units per wave (ILP latency hiding). Per-unit math
// is the verified r16 pipeline, byte-for-byte. launch_bounds(256,2) gives the
// allocator a 256-VGPR budget so dual conv state (krpA+krpB ~128 + accs ~64)
// fits WITHOUT spilling (r6/r8/r10/r17 all spilled under tight caps).
// Phases: [qA,qB->LDS; kA,kB->regs] (latencies overlap) -> [convA || convB
// interleaved] -> [O-writes, one barrier] -> back-half(A) -> back-half(B).
// ---------------------------------------------------------------------------
__global__ __launch_bounds__(256, 2) void attn_kernel(const float* __restrict__ qkv,
                                                      const float* __restrict__ bias2,
                                                      float* __restrict__ out) {
    // per-unit 9216B region: q [64][36] f32 -> O [64][36] f32 -> P [64][72] bf16
    __shared__ float smem[8][64 * 36];

    const int t = threadIdx.x;
    const int w = t >> 6;
    const int lane = t & 63;
    const int u0 = (blockIdx.x * 4 + w) * 2;
    const int u1 = u0 + 1;
    const int b0 = u0 / 3, h0 = u0 % 3;
    const int b1 = u1 / 3, h1 = u1 % 3;

    float* QsA = smem[w * 2];
    float* QsB = smem[w * 2 + 1];
    const float* baseA = qkv + (size_t)b0 * (64 * 288) + h0 * 32;
    const float* baseB = qkv + (size_t)b1 * (64 * 288) + h1 * 32;
    const float QS = 0.17677669529663687f * LOG2E;   // 32^-0.5 * log2e
    const int dd = lane & 31, H2 = lane >> 5;
    const int g = lane >> 4, c = lane & 15;

    // ---- q -> LDS (scaled) for both units, coalesced float4 ----
    {
        const int nr = lane >> 3, d0 = (lane & 7) * 4;
        #pragma unroll
        for (int s = 0; s < 8; s++) {
            int n = 8 * s + nr;
            float4 qa = *(const float4*)(baseA + n * 288 + d0);
            float4 qb = *(const float4*)(baseB + n * 288 + d0);
            qa.x *= QS; qa.y *= QS; qa.z *= QS; qa.w *= QS;
            qb.x *= QS; qb.y *= QS; qb.z *= QS; qb.w *= QS;
            *(float4*)(QsA + n * 36 + d0) = qa;
            *(float4*)(QsB + n * 36 + d0) = qb;
        }
    }

    // ---- k reversed-pairs for both units, rows rotated by 4*H2 ----
    f16x2 krpA[64], krpB[64];
    #pragma unroll
    for (int t8 = 0; t8 < 8; t8++) {
        const int rb = ((t8 + 4 * H2) & 7) * 8;
        float kA[8], kB[8];
        #pragma unroll
        for (int tx = 0; tx < 8; tx++) {
            kA[tx] = baseA[(rb + tx) * 288 + 96 + dd];
            kB[tx] = baseB[(rb + tx) * 288 + 96 + dd];
        }
        #pragma unroll
        for (int i = 0; i < 8; i++) {
            krpA[t8 * 8 + i] = __builtin_amdgcn_cvt_pkrtz(kA[i], kA[(i - 1) & 7]);
            krpB[t8 * 8 + i] = __builtin_amdgcn_cvt_pkrtz(kB[i], kB[(i - 1) & 7]);
        }
    }

    asm volatile("s_waitcnt lgkmcnt(0)" ::: "memory");

    // ---- stage 1: both 8x8 cyclic convs, interleaved (independent chains) ----
    float accA[4][8], accB[4][8];
    #pragma unroll
    for (int yi = 0; yi < 4; yi++)
        #pragma unroll
        for (int x = 0; x < 8; x++) { accA[yi][x] = 0.f; accB[yi][x] = 0.f; }

    #pragma unroll
    for (int u = 0; u < 8; u++) {
        f16x2 q2A[4], q2B[4];
        #pragma unroll
        for (int j = 0; j < 4; j++) {
            q2A[j] = __builtin_amdgcn_cvt_pkrtz(QsA[(u * 8 + 2 * j) * 36 + dd],
                                                QsA[(u * 8 + 2 * j + 1) * 36 + dd]);
            q2B[j] = __builtin_amdgcn_cvt_pkrtz(QsB[(u * 8 + 2 * j) * 36 + dd],
                                                QsB[(u * 8 + 2 * j + 1) * 36 + dd]);
        }
        #pragma unroll
        for (int yi = 0; yi < 4; yi++) {
            const int s = (yi - u) & 7;
            #pragma unroll
            for (int x = 0; x < 8; x++) {
                #pragma unroll
                for (int j = 0; j < 4; j++) {
                    accA[yi][x] = __builtin_amdgcn_fdot2(
                        q2A[j], krpA[s * 8 + ((x - 2 * j) & 7)], accA[yi][x], false);
                    accB[yi][x] = __builtin_amdgcn_fdot2(
                        q2B[j], krpB[s * 8 + ((x - 2 * j) & 7)], accB[yi][x], false);
                }
            }
        }
    }

    // ---- O into LDS for both units ----
    #pragma unroll
    for (int yi = 0; yi < 4; yi++) {
        const int n = (4 * H2 + yi) * 8;
        #pragma unroll
        for (int x = 0; x < 8; x++) {
            QsA[(n + x) * 36 + dd] = accA[yi][x];
            QsB[(n + x) * 36 + dd] = accB[yi][x];
        }
    }
    asm volatile("s_waitcnt lgkmcnt(0)" ::: "memory");

    // ---- per-unit back half (verified r16 pipeline) ----
    auto back_half = [&](const float* base, float* Qs, int h, int b) {
        // A-frags of O (hi/lo bf16): row = 16*mt + c, k-chunk = 8*g
        short8v Oh[4], Ol[4];
        #pragma unroll
        for (int mt = 0; mt < 4; mt++) {
            const float* rp = Qs + (16 * mt + c) * 36 + 8 * g;
            float4 x0 = *(const float4*)rp;
            float4 x1 = *(const float4*)(rp + 4);
            float xs[8] = {x0.x, x0.y, x0.z, x0.w, x1.x, x1.y, x1.z, x1.w};
            #pragma unroll
            for (int j = 0; j < 8; j++) {
                unsigned short hb = f2bf(xs[j]);
                Oh[mt][j] = (short)hb;
                Ol[mt][j] = (short)f2bf(xs[j] - bf2f(hb));
            }
        }

        // B-frags of V^T (hi/lo) from global
        short8v Vh[4], Vl[4];
        #pragma unroll
        for (int nt = 0; nt < 4; nt++) {
            const float* vp = base + (16 * nt + c) * 288 + 192 + 8 * g;
            float4 x0 = *(const float4*)vp;
            float4 x1 = *(const float4*)(vp + 4);
            float xs[8] = {x0.x, x0.y, x0.z, x0.w, x1.x, x1.y, x1.z, x1.w};
            #pragma unroll
            for (int j = 0; j < 8; j++) {
                unsigned short hb = f2bf(xs[j]);
                Vh[nt][j] = (short)hb;
                Vl[nt][j] = (short)f2bf(xs[j] - bf2f(hb));
            }
        }

        // S = O * V^T via MFMA (bias C-init; hh+hl+lh ~= fp32)
        const float* bb = bias2 + (size_t)h * 16 * 256 + lane * 4;
        f32x4 S[4][4];
        __builtin_amdgcn_s_setprio(1);
        #pragma unroll
        for (int mt = 0; mt < 4; mt++)
            #pragma unroll
            for (int nt = 0; nt < 4; nt++) {
                f32x4 a = __builtin_bit_cast(f32x4, *(const float4*)(bb + (mt * 4 + nt) * 256));
                a = __builtin_amdgcn_mfma_f32_16x16x32_bf16(Oh[mt], Vh[nt], a, 0, 0, 0);
                a = __builtin_amdgcn_mfma_f32_16x16x32_bf16(Oh[mt], Vl[nt], a, 0, 0, 0);
                a = __builtin_amdgcn_mfma_f32_16x16x32_bf16(Ol[mt], Vh[nt], a, 0, 0, 0);
                S[mt][nt] = a;
            }
        __builtin_amdgcn_s_setprio(0);

        // prefetch V for PV stage
        float vb[2][2][8];
        #pragma unroll
        for (int kt = 0; kt < 2; kt++)
            #pragma unroll
            for (int dt = 0; dt < 2; dt++)
                #pragma unroll
                for (int j = 0; j < 8; j++)
                    vb[kt][dt][j] = base[(32 * kt + 8 * g + j) * 288 + 192 + 16 * dt + c];

        // softmax: max-subtract (shfl) + exp2; SUM deferred to ones-MFMA
        #pragma unroll
        for (int mt = 0; mt < 4; mt++) {
            #pragma unroll
            for (int r = 0; r < 4; r++) {
                float m0 = fmaxf(fmaxf(S[mt][0][r], S[mt][1][r]),
                                 fmaxf(S[mt][2][r], S[mt][3][r]));
                m0 = fmaxf(m0, __shfl_xor(m0, 1, 64));
                m0 = fmaxf(m0, __shfl_xor(m0, 2, 64));
                m0 = fmaxf(m0, __shfl_xor(m0, 4, 64));
                m0 = fmaxf(m0, __shfl_xor(m0, 8, 64));
                #pragma unroll
                for (int nt = 0; nt < 4; nt++)
                    S[mt][nt][r] = exp2_fast(S[mt][nt][r] - m0);
            }
        }

        // P (unnormalized, <=1) -> LDS bf16 [64][72] (aliases O region)
        unsigned short* Ps = (unsigned short*)Qs;
        #pragma unroll
        for (int mt = 0; mt < 4; mt++)
            #pragma unroll
            for (int nt = 0; nt < 4; nt++)
                #pragma unroll
                for (int r = 0; r < 4; r++)
                    Ps[(16 * mt + 4 * g + r) * 72 + 16 * nt + c] = f2bf(S[mt][nt][r]);
        asm volatile("s_waitcnt lgkmcnt(0)" ::: "memory");

        // P A-frags
        short8v Pf[4][2];
        #pragma unroll
        for (int mt = 0; mt < 4; mt++)
            #pragma unroll
            for (int kt = 0; kt < 2; kt++)
                Pf[mt][kt] = *(const short8v*)(Ps + (16 * mt + c) * 72 + 32 * kt + 8 * g);

        // V B-frags for PV (single bf16)
        short8v Vp[2][2];
        #pragma unroll
        for (int kt = 0; kt < 2; kt++)
            #pragma unroll
            for (int dt = 0; dt < 2; dt++)
                #pragma unroll
                for (int j = 0; j < 8; j++)
                    Vp[kt][dt][j] = (short)f2bf(vb[kt][dt][j]);

        // row sums via ones-MFMA; inv via plain division (hazard-safe)
        short8v ones;
        #pragma unroll
        for (int j = 0; j < 8; j++) ones[j] = (short)0x3F80;   // bf16 1.0
        f32x4 inv4[4];
        __builtin_amdgcn_s_setprio(1);
        #pragma unroll
        for (int mt = 0; mt < 4; mt++) {
            f32x4 sa = {0.f, 0.f, 0.f, 0.f};
            sa = __builtin_amdgcn_mfma_f32_16x16x32_bf16(Pf[mt][0], ones, sa, 0, 0, 0);
            sa = __builtin_amdgcn_mfma_f32_16x16x32_bf16(Pf[mt][1], ones, sa, 0, 0, 0);
            #pragma unroll
            for (int r = 0; r < 4; r++) inv4[mt][r] = 1.f / sa[r];
        }

        // X = P * V via MFMA
        f32x4 X[4][2];
        #pragma unroll
        for (int mt = 0; mt < 4; mt++)
            #pragma unroll
            for (int dt = 0; dt < 2; dt++) {
                f32x4 a = {0.f, 0.f, 0.f, 0.f};
                a = __builtin_amdgcn_mfma_f32_16x16x32_bf16(Pf[mt][0], Vp[0][dt], a, 0, 0, 0);
                a = __builtin_amdgcn_mfma_f32_16x16x32_bf16(Pf[mt][1], Vp[1][dt], a, 0, 0, 0);
                X[mt][dt] = a;
            }
        __builtin_amdgcn_s_setprio(0);

        // normalize + store
        float* op = out + (size_t)b * (64 * 96) + h * 32;
        #pragma unroll
        for (int mt = 0; mt < 4; mt++)
            #pragma unroll
            for (int dt = 0; dt < 2; dt++)
                #pragma unroll
                for (int r = 0; r < 4; r++)
                    op[(16 * mt + 4 * g + r) * 96 + 16 * dt + c] = X[mt][dt][r] * inv4[mt][r];
    };

    back_half(baseA, QsA, h0, b0);
    back_half(baseB, QsB, h1, b1);
}

extern "C" void kernel_launch(void* const* d_in, const int* in_sizes, int n_in,
                              void* d_out, int out_size, void* d_ws, size_t ws_size,
                              hipStream_t stream) {
    const float* qkv = (const float*)d_in[0];
    const float* w1  = (const float*)d_in[1];
    const float* b1  = (const float*)d_in[2];
    const float* w2  = (const float*)d_in[3];
    const float* b2  = (const float*)d_in[4];
    float* out = (float*)d_out;
    float* bias2 = (float*)d_ws;   // 48 KB

    bias_kernel<<<192, 256, 0, stream>>>(w1, b1, w2, b2, bias2);
    // 8 units per block (4 waves x 2 units) -> 6144/8 = 768 blocks
    attn_kernel<<<(B_TOT * NHEAD) / 8, 256, 0, stream>>>(qkv, bias2, out);
}

// Round 19
// 60.581 us; speedup vs baseline: 1.2716x; 1.2716x over previous
//
#include <hip/hip_runtime.h>

#define B_TOT 2048
#define NHEAD 3

typedef __attribute__((ext_vector_type(8))) short short8v;
typedef __attribute__((ext_vector_type(4))) float f32x4;
typedef __attribute__((ext_vector_type(2))) __fp16 f16x2;

typedef __attribute__((address_space(1))) const void* gas_ptr;
typedef __attribute__((address_space(3))) void* las_ptr;

#define LOG2E 1.4426950408889634f

static __device__ __forceinline__ unsigned short f2bf(float x) {
    unsigned u = __builtin_bit_cast(unsigned, x);
    u += 0x7FFFu + ((u >> 16) & 1u);
    return (unsigned short)(u >> 16);
}
static __device__ __forceinline__ float bf2f(unsigned short s) {
    unsigned u = ((unsigned)s) << 16;
    return __builtin_bit_cast(float, u);
}
static __device__ __forceinline__ float exp2_fast(float x) {
    float r; asm("v_exp_f32 %0, %1" : "=v"(r) : "v"(x)); return r;
}

// ---------------------------------------------------------------------------
// Bias MLP precompute, 4-way j-split (verified r17). Layout (r7-r18):
//   bias2[((h*16 + mt*4 + nt) * 64 + lane) * 4 + r], pre-scaled by log2e.
// ---------------------------------------------------------------------------
__global__ __launch_bounds__(256) void bias_kernel(const float* __restrict__ w1,
                                                   const float* __restrict__ b1,
                                                   const float* __restrict__ w2,
                                                   const float* __restrict__ b2,
                                                   float* __restrict__ bias2) {
    int gtid = blockIdx.x * 256 + threadIdx.x;   // 0..49151
    int t = gtid >> 2, sub = gtid & 3;           // t: output index 0..12287
    int h = t >> 12;
    int lane = (t >> 6) & 63;
    int pair = t & 63;
    int g = lane >> 4, c = lane & 15;
    int mt = pair >> 4, nt = (pair >> 2) & 3, r = pair & 3;
    int n = 16 * mt + 4 * g + r;
    int m = 16 * nt + c;

    float d0 = (float)((n >> 3) - (m >> 3));
    float d1 = (float)((n & 7) - (m & 7));
    float r0 = (d0 > 0.f ? 1.f : (d0 < 0.f ? -1.f : 0.f)) * log1pf(fabsf(d0));
    float r1 = (d1 > 0.f ? 1.f : (d1 < 0.f ? -1.f : 0.f)) * log1pf(fabsf(d1));
    float a = 0.f;
    for (int i = 0; i < 64; i++) {
        int j = 4 * i + sub;
        float hd = fmaf(r0, w1[j], fmaf(r1, w1[256 + j], b1[j]));
        hd = fmaxf(hd, 0.f);
        a = fmaf(hd, w2[j * 3 + h], a);
    }
    a += __shfl_xor(a, 1, 64);
    a += __shfl_xor(a, 2, 64);
    if (sub == 0)
        bias2[((h * 16 + mt * 4 + nt) * 64 + lane) * 4 + r] = (a + b2[h]) * LOG2E;
}

// ---------------------------------------------------------------------------
// Main kernel = round-16 verified pipeline (64.95us) with a restructured
// load head:
//  (1) k staged HBM->LDS directly via 8x global_load_lds width=16 into a
//      linear [64][32] f32 region (ONE exposed ~450cy latency instead of 8
//      grouped load-wait cycles), then krp built from pipelined ds_reads.
//  (2) q global loads issued alongside the k-stage (latency shared), held in
//      regs through the krp pack, then scaled+stored to the SAME LDS region
//      (per-wave DS-FIFO orders q ds_writes after k ds_reads — the property
//      the verified q->O->P overlay already relies on).
//  (3) launch_bounds(256,2): r17/r18 showed (256,3) pins VGPR at 84 and
//      spills; (256,2) caps at 128. Peak need ~114, and 84 vs 128 are the
//      SAME occupancy bin (16 waves/CU) -> strictly safe.
// Kept verbatim from r16: dot2 conv, bias C-init, max-subtract softmax,
// ones-MFMA rowsum (inv via plain division), s_setprio MFMA clusters.
// ---------------------------------------------------------------------------
__global__ __launch_bounds__(256, 2) void attn_kernel(const float* __restrict__ qkv,
                                                      const float* __restrict__ bias2,
                                                      float* __restrict__ out) {
    // per-wave 9216B region: k [64][32] f32 (linear) -> q [64][36] f32
    //                        -> O [64][36] f32 -> P [64][72] bf16
    __shared__ float smem[4][64 * 36];

    const int t = threadIdx.x;
    const int w = t >> 6;
    const int lane = t & 63;
    const int h = blockIdx.x % 3;
    const int b = (blockIdx.x / 3) * 4 + w;

    float* Qs = smem[w];
    const float* base = qkv + (size_t)b * (64 * 288) + h * 32;
    const float QS = 0.17677669529663687f * LOG2E;   // 32^-0.5 * log2e
    const int dd = lane & 31, H2 = lane >> 5;
    const int g = lane >> 4, c = lane & 15;
    const int nr = lane >> 3, d0q = (lane & 7) * 4;

    // ---- k: HBM -> LDS direct, 8x global_load_lds (16B/lane, 1KB/instr).
    // LDS linear [64][32]: call s covers rows 8s..8s+7. ----
    #pragma unroll
    for (int s = 0; s < 8; s++) {
        const float* gsrc = base + (8 * s + nr) * 288 + 96 + d0q;
        __builtin_amdgcn_global_load_lds((gas_ptr)gsrc, (las_ptr)(Qs + s * 256),
                                         16, 0, 0);
    }

    // ---- q global loads issued now (share the latency window), kept in regs ----
    float4 qreg[8];
    #pragma unroll
    for (int s = 0; s < 8; s++)
        qreg[s] = *(const float4*)(base + (8 * s + nr) * 288 + d0q);

    asm volatile("s_waitcnt vmcnt(0)" ::: "memory");

    // ---- krp from LDS k (pipelined ds_reads), rows rotated by 4*H2:
    // krp[t8][i] = {k[i], k[(i-1)&7]} (f16x2) ----
    f16x2 krp[64];
    #pragma unroll
    for (int t8 = 0; t8 < 8; t8++) {
        const int rb = ((t8 + 4 * H2) & 7) * 8;
        float k8[8];
        #pragma unroll
        for (int tx = 0; tx < 8; tx++)
            k8[tx] = Qs[(rb + tx) * 32 + dd];
        #pragma unroll
        for (int i = 0; i < 8; i++)
            krp[t8 * 8 + i] = __builtin_amdgcn_cvt_pkrtz(k8[i], k8[(i - 1) & 7]);
    }
    __builtin_amdgcn_sched_barrier(0);

    // ---- q -> LDS (scaled) [64][36], overwrites k region (DS-FIFO safe) ----
    #pragma unroll
    for (int s = 0; s < 8; s++) {
        float4 q4 = qreg[s];
        q4.x *= QS; q4.y *= QS; q4.z *= QS; q4.w *= QS;
        *(float4*)(Qs + (8 * s + nr) * 36 + d0q) = q4;
    }
    asm volatile("s_waitcnt lgkmcnt(0)" ::: "memory");

    // ---- stage 1: 8x8 cyclic conv via f16 dot2, f32 accumulate ----
    float acc[4][8];
    #pragma unroll
    for (int yi = 0; yi < 4; yi++)
        #pragma unroll
        for (int x = 0; x < 8; x++) acc[yi][x] = 0.f;

    #pragma unroll
    for (int u = 0; u < 8; u++) {
        f16x2 q2[4];
        #pragma unroll
        for (int j = 0; j < 4; j++) {
            float qa = Qs[(u * 8 + 2 * j) * 36 + dd];
            float qb = Qs[(u * 8 + 2 * j + 1) * 36 + dd];
            q2[j] = __builtin_amdgcn_cvt_pkrtz(qa, qb);
        }
        #pragma unroll
        for (int yi = 0; yi < 4; yi++) {
            const int s = (yi - u) & 7;
            #pragma unroll
            for (int x = 0; x < 8; x++) {
                #pragma unroll
                for (int j = 0; j < 4; j++)
                    acc[yi][x] = __builtin_amdgcn_fdot2(
                        q2[j], krp[s * 8 + ((x - 2 * j) & 7)], acc[yi][x], false);
            }
        }
    }

    // ---- O into same LDS region ----
    #pragma unroll
    for (int yi = 0; yi < 4; yi++) {
        const int n = (4 * H2 + yi) * 8;
        #pragma unroll
        for (int x = 0; x < 8; x++)
            Qs[(n + x) * 36 + dd] = acc[yi][x];
    }
    asm volatile("s_waitcnt lgkmcnt(0)" ::: "memory");

    // ---- A-frags of O (hi/lo bf16): row = 16*mt + c, k-chunk = 8*g ----
    short8v Oh[4], Ol[4];
    #pragma unroll
    for (int mt = 0; mt < 4; mt++) {
        const float* rp = Qs + (16 * mt + c) * 36 + 8 * g;
        float4 x0 = *(const float4*)rp;
        float4 x1 = *(const float4*)(rp + 4);
        float xs[8] = {x0.x, x0.y, x0.z, x0.w, x1.x, x1.y, x1.z, x1.w};
        #pragma unroll
        for (int j = 0; j < 8; j++) {
            unsigned short hb = f2bf(xs[j]);
            Oh[mt][j] = (short)hb;
            Ol[mt][j] = (short)f2bf(xs[j] - bf2f(hb));
        }
    }

    // ---- B-frags of V^T (hi/lo): element V[16*nt + c][8*g + j], from global ----
    short8v Vh[4], Vl[4];
    #pragma unroll
    for (int nt = 0; nt < 4; nt++) {
        const float* vp = base + (16 * nt + c) * 288 + 192 + 8 * g;
        float4 x0 = *(const float4*)vp;
        float4 x1 = *(const float4*)(vp + 4);
        float xs[8] = {x0.x, x0.y, x0.z, x0.w, x1.x, x1.y, x1.z, x1.w};
        #pragma unroll
        for (int j = 0; j < 8; j++) {
            unsigned short hb = f2bf(xs[j]);
            Vh[nt][j] = (short)hb;
            Vl[nt][j] = (short)f2bf(xs[j] - bf2f(hb));
        }
    }

    // ---- S = O * V^T via MFMA (bias C-init; hh+hl+lh ~= fp32) ----
    const float* bb = bias2 + (size_t)h * 16 * 256 + lane * 4;
    f32x4 S[4][4];
    __builtin_amdgcn_s_setprio(1);
    #pragma unroll
    for (int mt = 0; mt < 4; mt++)
        #pragma unroll
        for (int nt = 0; nt < 4; nt++) {
            f32x4 a = __builtin_bit_cast(f32x4, *(const float4*)(bb + (mt * 4 + nt) * 256));
            a = __builtin_amdgcn_mfma_f32_16x16x32_bf16(Oh[mt], Vh[nt], a, 0, 0, 0);
            a = __builtin_amdgcn_mfma_f32_16x16x32_bf16(Oh[mt], Vl[nt], a, 0, 0, 0);
            a = __builtin_amdgcn_mfma_f32_16x16x32_bf16(Ol[mt], Vh[nt], a, 0, 0, 0);
            S[mt][nt] = a;
        }
    __builtin_amdgcn_s_setprio(0);

    // ---- prefetch V for PV stage (raw f32, packed later) ----
    float vb[2][2][8];   // [kt][dt][j] = V[32*kt + 8*g + j][16*dt + c]
    #pragma unroll
    for (int kt = 0; kt < 2; kt++)
        #pragma unroll
        for (int dt = 0; dt < 2; dt++)
            #pragma unroll
            for (int j = 0; j < 8; j++)
                vb[kt][dt][j] = base[(32 * kt + 8 * g + j) * 288 + 192 + 16 * dt + c];

    // ---- softmax: max-subtract (shfl) + exp2; SUM deferred to ones-MFMA ----
    #pragma unroll
    for (int mt = 0; mt < 4; mt++) {
        #pragma unroll
        for (int r = 0; r < 4; r++) {
            float m0 = fmaxf(fmaxf(S[mt][0][r], S[mt][1][r]), fmaxf(S[mt][2][r], S[mt][3][r]));
            m0 = fmaxf(m0, __shfl_xor(m0, 1, 64));
            m0 = fmaxf(m0, __shfl_xor(m0, 2, 64));
            m0 = fmaxf(m0, __shfl_xor(m0, 4, 64));
            m0 = fmaxf(m0, __shfl_xor(m0, 8, 64));
            #pragma unroll
            for (int nt = 0; nt < 4; nt++)
                S[mt][nt][r] = exp2_fast(S[mt][nt][r] - m0);
        }
    }

    // ---- P (unnormalized, <=1) -> LDS bf16 [64][72] (aliases O; O consumed) ----
    unsigned short* Ps = (unsigned short*)Qs;
    #pragma unroll
    for (int mt = 0; mt < 4; mt++)
        #pragma unroll
        for (int nt = 0; nt < 4; nt++)
            #pragma unroll
            for (int r = 0; r < 4; r++)
                Ps[(16 * mt + 4 * g + r) * 72 + 16 * nt + c] = f2bf(S[mt][nt][r]);
    asm volatile("s_waitcnt lgkmcnt(0)" ::: "memory");

    // ---- P A-frags: row = 16*mt + c, k-chunk = 32*kt + 8*g ----
    short8v Pf[4][2];
    #pragma unroll
    for (int mt = 0; mt < 4; mt++)
        #pragma unroll
        for (int kt = 0; kt < 2; kt++)
            Pf[mt][kt] = *(const short8v*)(Ps + (16 * mt + c) * 72 + 32 * kt + 8 * g);

    // ---- V B-frags for PV (single bf16) ----
    short8v Vp[2][2];
    #pragma unroll
    for (int kt = 0; kt < 2; kt++)
        #pragma unroll
        for (int dt = 0; dt < 2; dt++)
            #pragma unroll
            for (int j = 0; j < 8; j++)
                Vp[kt][dt][j] = (short)f2bf(vb[kt][dt][j]);

    // ---- row sums via ones-MFMA; inv via plain division (hazard-safe) ----
    short8v ones;
    #pragma unroll
    for (int j = 0; j < 8; j++) ones[j] = (short)0x3F80;   // bf16 1.0
    f32x4 inv4[4];
    __builtin_amdgcn_s_setprio(1);
    #pragma unroll
    for (int mt = 0; mt < 4; mt++) {
        f32x4 sa = {0.f, 0.f, 0.f, 0.f};
        sa = __builtin_amdgcn_mfma_f32_16x16x32_bf16(Pf[mt][0], ones, sa, 0, 0, 0);
        sa = __builtin_amdgcn_mfma_f32_16x16x32_bf16(Pf[mt][1], ones, sa, 0, 0, 0);
        #pragma unroll
        for (int r = 0; r < 4; r++) inv4[mt][r] = 1.f / sa[r];
    }

    // ---- X = P * V via MFMA ----
    f32x4 X[4][2];
    #pragma unroll
    for (int mt = 0; mt < 4; mt++)
        #pragma unroll
        for (int dt = 0; dt < 2; dt++) {
            f32x4 a = {0.f, 0.f, 0.f, 0.f};
            a = __builtin_amdgcn_mfma_f32_16x16x32_bf16(Pf[mt][0], Vp[0][dt], a, 0, 0, 0);
            a = __builtin_amdgcn_mfma_f32_16x16x32_bf16(Pf[mt][1], Vp[1][dt], a, 0, 0, 0);
            X[mt][dt] = a;
        }
    __builtin_amdgcn_s_setprio(0);

    // ---- normalize + store: out[b][n][h*32 + d] ----
    float* op = out + (size_t)b * (64 * 96) + h * 32;
    #pragma unroll
    for (int mt = 0; mt < 4; mt++)
        #pragma unroll
        for (int dt = 0; dt < 2; dt++)
            #pragma unroll
            for (int r = 0; r < 4; r++)
                op[(16 * mt + 4 * g + r) * 96 + 16 * dt + c] = X[mt][dt][r] * inv4[mt][r];
}

extern "C" void kernel_launch(void* const* d_in, const int* in_sizes, int n_in,
                              void* d_out, int out_size, void* d_ws, size_t ws_size,
                              hipStream_t stream) {
    const float* qkv = (const float*)d_in[0];
    const float* w1  = (const float*)d_in[1];
    const float* b1  = (const float*)d_in[2];
    const float* w2  = (const float*)d_in[3];
    const float* b2  = (const float*)d_in[4];
    float* out = (float*)d_out;
    float* bias2 = (float*)d_ws;   // 48 KB

    bias_kernel<<<192, 256, 0, stream>>>(w1, b1, w2, b2, bias2);
    attn_kernel<<<(B_TOT / 4) * NHEAD, 256, 0, stream>>>(qkv, bias2, out);
}